// Round 3
// baseline (1435.111 us; speedup 1.0000x reference)
//
#include <hip/hip_runtime.h>

typedef short bf8_t __attribute__((ext_vector_type(8)));   // 8 bf16 (4 VGPRs)
typedef float f32x4 __attribute__((ext_vector_type(4)));

#define SLOPE (11.0f / 48.0f)   // RReLU eval negative slope (1/8+1/3)/2

__device__ inline unsigned short f2b(float f) {
    union { float f; unsigned int i; } v; v.f = f;
    unsigned int x = v.i;
    return (unsigned short)((x + 0x7FFFu + ((x >> 16) & 1u)) >> 16);
}

// A-fragment loaders: bf16 direct, or fp32 + convert-in-register
__device__ inline bf8_t load_frag(const unsigned short* p) { return *(const bf8_t*)p; }
__device__ inline bf8_t load_frag(const float* p) {
    f32x4 a = *(const f32x4*)p;
    f32x4 b = *(const f32x4*)(p + 4);
    bf8_t r;
    r[0] = (short)f2b(a[0]); r[1] = (short)f2b(a[1]);
    r[2] = (short)f2b(a[2]); r[3] = (short)f2b(a[3]);
    r[4] = (short)f2b(b[0]); r[5] = (short)f2b(b[1]);
    r[6] = (short)f2b(b[2]); r[7] = (short)f2b(b[3]);
    return r;
}

// ---- transpose + convert W (R x 128, row-major, fp32) -> WT (128 x R, bf16) ----
__global__ void transpose_w(const float* __restrict__ W,
                            unsigned short* __restrict__ WT, int R) {
    int i = blockIdx.x * 256 + threadIdx.x;
    if (i < R * 128) {
        int r = i >> 7, n = i & 127;
        WT[(size_t)n * R + r] = f2b(W[i]);
    }
}

// ---- in-degree count ----
__global__ void count_k(const int* __restrict__ dst, int* __restrict__ cnt, int E) {
    int i = blockIdx.x * 256 + threadIdx.x;
    if (i < E) atomicAdd(&cnt[dst[i]], 1);
}

// ---- generic MFMA GEMM: C[M,128] = bf16(A[M, KH*128]) @ W, epilogue by MODE ----
// MODE 0: outF[r*128+col] = acc                                   (nodeT)
// MODE 1: v = acc + nodeT[src[r]][col] + bn[col]; atomicAdd agg[dst[r]][col]
// MODE 2: v = agg[r][col]/max(cnt,1) + acc + bl[col]; rrelu; hcat[r*256+colOff+col] (bf16)
// MODE 3: outF[r*128+col] = acc + bo[col]   (fp32 final output)
template <int KH, int MODE, typename AT>
__global__ __launch_bounds__(256) void gemm_k(
    const AT* __restrict__ A, int sA, int M,
    const unsigned short* __restrict__ WT, int sWT,
    const float* __restrict__ bias,
    const float* __restrict__ nodeT, const int* __restrict__ src,
    const int* __restrict__ dst, float* __restrict__ agg,
    const float* __restrict__ aggIn, const int* __restrict__ cnt,
    unsigned short* __restrict__ hcat, int colOff,
    float* __restrict__ outF) {
    // LDS: W^T tile, 128 n-rows x 128 k-cols, stride 136 (pad 8 -> 2-way free banks)
    __shared__ unsigned short lds[128 * 136];
    const int tid = threadIdx.x;
    const int wave = tid >> 6, lane = tid & 63;
    const int l15 = lane & 15, kg = lane >> 4;
    const int rBase = blockIdx.x * 128 + wave * 32;   // 4 waves x 32 rows

    f32x4 acc[2][8];
    const f32x4 zero = {0.f, 0.f, 0.f, 0.f};
    for (int g = 0; g < 2; g++)
        for (int t = 0; t < 8; t++) acc[g][t] = zero;

    for (int kh = 0; kh < KH; kh++) {
        // stage W^T half into LDS (vectorized b128 writes)
        for (int c = tid; c < 2048; c += 256) {
            int n = c >> 4, k0 = (c & 15) << 3;
            bf8_t v = *(const bf8_t*)(WT + (size_t)n * sWT + kh * 128 + k0);
            *(bf8_t*)(lds + n * 136 + k0) = v;
        }
        __syncthreads();

        int r0 = rBase + l15, r1 = rBase + 16 + l15;
        int cr0 = r0 < M ? r0 : M - 1;
        int cr1 = r1 < M ? r1 : M - 1;
        const AT* a0p = A + (size_t)cr0 * sA + kh * 128 + kg * 8;
        const AT* a1p = A + (size_t)cr1 * sA + kh * 128 + kg * 8;
#pragma unroll
        for (int kc = 0; kc < 4; kc++) {
            bf8_t a0 = load_frag(a0p + kc * 32);
            bf8_t a1 = load_frag(a1p + kc * 32);
#pragma unroll
            for (int nt = 0; nt < 8; nt++) {
                bf8_t b = *(const bf8_t*)(lds + (nt * 16 + l15) * 136 + kc * 32 + kg * 8);
                acc[0][nt] = __builtin_amdgcn_mfma_f32_16x16x32_bf16(a0, b, acc[0][nt], 0, 0, 0);
                acc[1][nt] = __builtin_amdgcn_mfma_f32_16x16x32_bf16(a1, b, acc[1][nt], 0, 0, 0);
            }
        }
        if (kh + 1 < KH) __syncthreads();
    }

    // epilogue: lane holds D[m = kg*4+reg][n = l15] of each 16x16 tile
#pragma unroll
    for (int g = 0; g < 2; g++) {
#pragma unroll
        for (int reg = 0; reg < 4; reg++) {
            int r = rBase + g * 16 + kg * 4 + reg;
            if (r >= M) continue;
            if constexpr (MODE == 0) {
#pragma unroll
                for (int nt = 0; nt < 8; nt++) {
                    int col = nt * 16 + l15;
                    outF[(size_t)r * 128 + col] = acc[g][nt][reg];
                }
            } else if constexpr (MODE == 1) {
                int s = src[r], d = dst[r];
                const float* np_ = nodeT + (size_t)s * 128;
                float* ap = agg + (size_t)d * 128;
#pragma unroll
                for (int nt = 0; nt < 8; nt++) {
                    int col = nt * 16 + l15;
                    float v = acc[g][nt][reg] + np_[col] + bias[col];
                    unsafeAtomicAdd(ap + col, v);
                }
            } else if constexpr (MODE == 2) {
                float c = (float)cnt[r];
                float inv = 1.0f / fmaxf(c, 1.0f);
#pragma unroll
                for (int nt = 0; nt < 8; nt++) {
                    int col = nt * 16 + l15;
                    float v = aggIn[(size_t)r * 128 + col] * inv + acc[g][nt][reg] + bias[col];
                    v = v >= 0.f ? v : v * SLOPE;
                    hcat[(size_t)r * 256 + colOff + col] = f2b(v);
                }
            } else {  // MODE 3: fp32 output
#pragma unroll
                for (int nt = 0; nt < 8; nt++) {
                    int col = nt * 16 + l15;
                    outF[(size_t)r * 128 + col] = acc[g][nt][reg] + bias[col];
                }
            }
        }
    }
}

extern "C" void kernel_launch(void* const* d_in, const int* in_sizes, int n_in,
                              void* d_out, int out_size, void* d_ws, size_t ws_size,
                              hipStream_t stream) {
    const float* node_feats = (const float*)d_in[0];
    const float* edge_feats = (const float*)d_in[1];
    const int* src = (const int*)d_in[2];
    const int* dst = (const int*)d_in[3];
    const float* Wn0 = (const float*)d_in[4];
    const float* bn0 = (const float*)d_in[5];
    const float* Wl0 = (const float*)d_in[6];
    const float* bl0 = (const float*)d_in[7];
    const float* Wn1 = (const float*)d_in[8];
    const float* bn1 = (const float*)d_in[9];
    const float* Wl1 = (const float*)d_in[10];
    const float* bl1 = (const float*)d_in[11];
    const float* Wo = (const float*)d_in[12];
    const float* bo = (const float*)d_in[13];

    const int N = in_sizes[0] / 128;
    const int E = in_sizes[2];

    char* ws = (char*)d_ws;
    float* nodeT = (float*)ws;              ws += (size_t)N * 128 * 4;
    float* agg = (float*)ws;                ws += (size_t)N * 128 * 4;
    int* cnt = (int*)ws;                    ws += (size_t)N * 4;
    unsigned short* hcat = (unsigned short*)ws;  ws += (size_t)N * 256 * 2;
    unsigned short* WTn0 = (unsigned short*)ws;  ws += (size_t)128 * 256 * 2;
    unsigned short* WTl0 = (unsigned short*)ws;  ws += (size_t)128 * 128 * 2;
    unsigned short* WTn1 = (unsigned short*)ws;  ws += (size_t)128 * 256 * 2;
    unsigned short* WTl1 = (unsigned short*)ws;  ws += (size_t)128 * 128 * 2;
    unsigned short* WTo = (unsigned short*)ws;   ws += (size_t)128 * 256 * 2;

    float* outF = (float*)d_out;

    const int gN = (N + 127) / 128;   // node-GEMM blocks
    const int gE = (E + 127) / 128;   // edge-GEMM blocks

    // zero agg + cnt (contiguous)
    hipMemsetAsync(agg, 0, (size_t)N * 128 * 4 + (size_t)N * 4, stream);

    // pre-transpose + convert weights (tiny)
    transpose_w<<<128, 256, 0, stream>>>(Wn0, WTn0, 256);
    transpose_w<<<64, 256, 0, stream>>>(Wl0, WTl0, 128);
    transpose_w<<<128, 256, 0, stream>>>(Wn1, WTn1, 256);
    transpose_w<<<64, 256, 0, stream>>>(Wl1, WTl1, 128);
    transpose_w<<<128, 256, 0, stream>>>(Wo, WTo, 256);

    count_k<<<(E + 255) / 256, 256, 0, stream>>>(dst, cnt, E);

    // ---- layer 0 ----
    gemm_k<1, 0, float><<<gN, 256, 0, stream>>>(node_feats, 128, N, WTn0, 256, nullptr,
        nullptr, nullptr, nullptr, nullptr, nullptr, nullptr, nullptr, 0, nodeT);
    gemm_k<1, 1, float><<<gE, 256, 0, stream>>>(edge_feats, 128, E, WTn0 + 128, 256, bn0,
        nodeT, src, dst, agg, nullptr, nullptr, nullptr, 0, nullptr);
    gemm_k<1, 2, float><<<gN, 256, 0, stream>>>(node_feats, 128, N, WTl0, 128, bl0,
        nullptr, nullptr, nullptr, nullptr, agg, cnt, hcat, 0, nullptr);

    // ---- layer 1 ----
    hipMemsetAsync(agg, 0, (size_t)N * 128 * 4, stream);
    gemm_k<1, 0, unsigned short><<<gN, 256, 0, stream>>>(hcat, 256, N, WTn1, 256, nullptr,
        nullptr, nullptr, nullptr, nullptr, nullptr, nullptr, nullptr, 0, nodeT);
    gemm_k<1, 1, float><<<gE, 256, 0, stream>>>(edge_feats, 128, E, WTn1 + 128, 256, bn1,
        nodeT, src, dst, agg, nullptr, nullptr, nullptr, 0, nullptr);
    gemm_k<1, 2, unsigned short><<<gN, 256, 0, stream>>>(hcat, 256, N, WTl1, 128, bl1,
        nullptr, nullptr, nullptr, nullptr, agg, cnt, hcat, 128, nullptr);

    // ---- output: [hA|hB] @ Wo + bo  (fp32 out) ----
    gemm_k<2, 3, unsigned short><<<gN, 256, 0, stream>>>(hcat, 256, N, WTo, 256, bo,
        nullptr, nullptr, nullptr, nullptr, nullptr, nullptr, nullptr, 0, outF);
}